// Round 7
// baseline (115.683 us; speedup 1.0000x reference)
//
#include <hip/hip_runtime.h>

// Problem constants
#define NPX    2097152                // 4*512*1024 pixels per head
#define NPX4   (NPX/4)
#define CH_STR 8192                   // 64*128
#define IMG_STR 155648                // 19*8192
#define LOG2E  1.4426950408889634f
#define LN2    0.6931471805599453f

// Workspace: prob[2*NPX] floats at ws start, control region after.
#define OFF_CTL   (2ull*NPX*4)
// ctl layout in u32 units
#define CTL_HIST    0                   // [3 levels][2 heads][4096] = 24576
#define CTL_BAR     24576               // u[2] software grid barrier (cnt, gen)
#define CTL_PREFIX  24578               // u[2]
#define CTL_KREM    24580               // u[2]
#define CTL_THR     24582               // f[2]
#define CTL_PPSUM   24584               // f[2*1024] pass1 per-block partials
#define CTL_PPCNT   28680               // u[2*1024]
#define CTL_OPSUM   32776               // f[2*256]
#define CTL_OPCNT   33288               // u[2*256]
#define CTL_BPS     33800               // f[512*2]
#define CTL_BPC     34824               // u[512*2]

// ---------------------------------------------------------------------------
// Pass 1: blocks [0,2048) = OHEM, TWO output rows per block (half-block each).
// Per row, the vertically-interpolated source row is staged in LDS as
// (e[x],e[x+1]) float2 pairs. A thread covers 8 consecutive output px whose
// x0 spans only {X,X+1}, so 2 ds_read_b64 per channel feed all 8 lerps.
// Weights are pre-scaled by log2(e): inner loop = mul+fma+fma+v_exp+add.
// Blocks [2048,2560) = boundary BCE. No atomics; partials to private slots.
// ---------------------------------------------------------------------------
__global__ __launch_bounds__(256, 4) void fused_pass1(
    const float* __restrict__ mp, const float* __restrict__ cp,
    const float* __restrict__ bp, const int* __restrict__ seg,
    const float* __restrict__ bg,
    float* __restrict__ probA, float* __restrict__ ppsum, unsigned* __restrict__ ppcnt,
    float* __restrict__ bps, unsigned* __restrict__ bpc, unsigned* __restrict__ bar)
{
    __shared__ float2 erow[2 * 19 * 128];      // 38912 B
    __shared__ float rf[4]; __shared__ unsigned ru[4];
    __shared__ float rf2[4]; __shared__ unsigned ru2[4];
    int bk = blockIdx.x;
    int tid = threadIdx.x;

    if (bk == 0 && tid < 2) bar[tid] = 0u;     // init software barrier

    if (bk < 2048) {
        int row0 = bk << 1;                    // global row pair (never straddles head/sample)
        int head = row0 >> 11;
        int r0i  = row0 & 2047;
        int b    = r0i >> 9;
        int yA   = r0i & 511;
        const float* pred = head ? cp : mp;

        // stage both rows' vertically-interpolated channels
        for (int r = 0; r < 2; ++r) {
            int y = yA + r;
            float fy = (float)y * (63.0f / 511.0f);
            int y0 = min((int)fy, 63);
            int y1 = min(y0 + 1, 63);
            float wy = fy - (float)y0;
            const float* r0 = pred + (size_t)b * IMG_STR + y0 * 128;
            const float* r1 = pred + (size_t)b * IMG_STR + y1 * 128;
            float2* er = erow + r * 2432;
            for (int i = tid; i < 2432; i += 256) {
                int c = i >> 7, x = i & 127;
                float v0 = r0[c * CH_STR + x];
                float v1 = r1[c * CH_STR + x];
                float e = fmaf(wy, v1 - v0, v0);
                er[c * 128 + x].x = e;
                if (x > 0)    er[c * 128 + x - 1].y = e;
                if (x == 127) er[c * 128 + 127].y = e;   // pad; weight is 0 there
            }
        }
        __syncthreads();

        int half = tid >> 7;                   // which row this thread works
        int xi   = tid & 127;
        int xb   = xi << 3;                    // 8 px per thread
        int y    = yA + half;
        int P    = (b * 512 + y) * 1024 + xb;
        const float2* er = erow + half * 2432;

        int4 ta = *(const int4*)(seg + P);
        int4 tb = *(const int4*)(seg + P + 4);
        int t[8] = {ta.x, ta.y, ta.z, ta.w, tb.x, tb.y, tb.z, tb.w};

        float fx0 = (float)xb * (127.0f / 1023.0f);
        int X = min((int)fx0, 126);            // taps e[X], e[X+1], e[X+2]
        float wA[8], wB[8], wC[8];
#pragma unroll
        for (int dx = 0; dx < 8; ++dx) {
            float fx = (float)(xb + dx) * (127.0f / 1023.0f);
            int x0 = min((int)fx, 127);
            float wx = fx - (float)x0;
            bool sm = (x0 == X);
            wA[dx] = sm ? (1.0f - wx) * LOG2E : 0.0f;
            wB[dx] = (sm ? wx : (1.0f - wx)) * LOG2E;
            wC[dx] = sm ? 0.0f : wx * LOG2E;
        }

        float s[8] = {0.f, 0.f, 0.f, 0.f, 0.f, 0.f, 0.f, 0.f};
#pragma unroll
        for (int c = 0; c < 19; ++c) {
            float2 eA = er[c * 128 + X];       // (e[X],   e[X+1])
            float2 eB = er[c * 128 + X + 1];   // (e[X+1], e[X+2])
#pragma unroll
            for (int dx = 0; dx < 8; ++dx) {
                float l2 = fmaf(eA.x, wA[dx], fmaf(eA.y, wB[dx], eB.y * wC[dx]));
                s[dx] += __builtin_exp2f(l2);  // v_exp_f32, base-2
            }
        }

        float fs = 0.f; unsigned ic = 0;
        float pr[8];
#pragma unroll
        for (int dx = 0; dx < 8; ++dx) {
            bool valid = (t[dx] != 255);
            int tc = valid ? t[dx] : 0;
            float2 eA = er[tc * 128 + X];
            float2 eB = er[tc * 128 + X + 1];
            float lt2 = fmaf(eA.x, wA[dx], fmaf(eA.y, wB[dx], eB.y * wC[dx]));  // bit-identical
            float ls2 = __builtin_log2f(s[dx]);           // v_log_f32
            float n   = LN2 * (ls2 - lt2);                // nll (natural log)
            float p   = fminf(__builtin_exp2f(lt2 - ls2), 1.0f);
            pr[dx] = valid ? p : 1.0f;
            if (valid && p <= 0.7f) { fs += n; ic++; }
        }
        float* pb = probA + (size_t)head * NPX + P;
        *(float4*)pb       = make_float4(pr[0], pr[1], pr[2], pr[3]);
        *(float4*)(pb + 4) = make_float4(pr[4], pr[5], pr[6], pr[7]);

        for (int o = 32; o; o >>= 1) {
            fs += __shfl_down(fs, o, 64);
            ic += (unsigned)__shfl_down((int)ic, o, 64);
        }
        int wave = tid >> 6, lane = tid & 63;
        if (lane == 0) { rf[wave] = fs; ru[wave] = ic; }
        __syncthreads();
        if (tid == 0) {
            ppsum[head * 1024 + (bk & 1023)] = rf[0] + rf[1] + rf[2] + rf[3];
            ppcnt[head * 1024 + (bk & 1023)] = ru[0] + ru[1] + ru[2] + ru[3];
        }
    } else {
        // -------- boundary BCE --------
        int bb = bk - 2048;                   // [0,512)
        int b  = bb >> 7;                     // 128 blocks per sample
        int blk = bb & 127;
        float psum = 0.f, nsum = 0.f; unsigned pc = 0, nc = 0;

        for (int g = blk * 256 + tid; g < 131072; g += 128 * 256) {
            int P = g << 2;
            int y = P >> 10, xb = P & 1023;

            float fy = (float)y * (63.0f / 511.0f);
            int y0 = min((int)fy, 63);
            int y1 = min(y0 + 1, 63);
            float wy = fy - (float)y0;

            const float* r0 = bp + b * 8192 + y0 * 128;
            const float* r1 = bp + b * 8192 + y1 * 128;
            float fx0 = (float)xb * (127.0f / 1023.0f);
            int X  = min((int)fx0, 126);
            int X2 = min(X + 2, 127);
            float c0 = r0[X], c1 = r0[X + 1], c2 = r0[X2];
            float d0 = r1[X], d1 = r1[X + 1], d2 = r1[X2];
            float e0 = fmaf(wy, d0 - c0, c0);
            float e1 = fmaf(wy, d1 - c1, c1);
            float e2 = fmaf(wy, d2 - c2, c2);

            float4 t4 = *(const float4*)(bg + (size_t)b * 524288 + P);
            float tv[4] = {t4.x, t4.y, t4.z, t4.w};

#pragma unroll
            for (int dx = 0; dx < 4; ++dx) {
                float fx = (float)(xb + dx) * (127.0f / 1023.0f);
                int x0 = min((int)fx, 127);
                int x1 = min(x0 + 1, 127);
                float wx = fx - (float)x0;
                float a0 = (x0 == X)     ? e0 : e1;
                float a1 = (x1 == X + 1) ? e1 : e2;
                float p  = fmaf(wx, a1 - a0, a0);
                bool isp = (tv[dx] == 1.0f);
                bool isn = (tv[dx] == 0.0f);
                float q = isp ? p : 1.0f - p;
                float l = fmaxf(__logf(q), -100.0f);
                if (isp) { pc++; psum -= l; }
                if (isn) { nc++; nsum -= l; }
            }
        }
        for (int o = 32; o; o >>= 1) {
            psum += __shfl_down(psum, o, 64);
            nsum += __shfl_down(nsum, o, 64);
            pc   += (unsigned)__shfl_down((int)pc, o, 64);
            nc   += (unsigned)__shfl_down((int)nc, o, 64);
        }
        int wave = tid >> 6, lane = tid & 63;
        if (lane == 0) { rf[wave] = psum; rf2[wave] = nsum; ru[wave] = pc; ru2[wave] = nc; }
        __syncthreads();
        if (tid == 0) {
            bps[2 * bb]     = rf[0] + rf[1] + rf[2] + rf[3];
            bps[2 * bb + 1] = rf2[0] + rf2[1] + rf2[2] + rf2[3];
            bpc[2 * bb]     = ru[0] + ru[1] + ru[2] + ru[3];
            bpc[2 * bb + 1] = ru2[0] + ru2[1] + ru2[2] + ru2[3];
        }
    }
}

// ---------------------------------------------------------------------------
// Software grid barrier (sense-reversing), agent scope. SLOW PATH ONLY.
// ---------------------------------------------------------------------------
__device__ __forceinline__ void gbar(unsigned* bar, int tid) {
    __syncthreads();
    if (tid == 0) {
        unsigned g = __hip_atomic_load(&bar[1], __ATOMIC_RELAXED, __HIP_MEMORY_SCOPE_AGENT);
        unsigned t = __hip_atomic_fetch_add(&bar[0], 1u, __ATOMIC_ACQ_REL, __HIP_MEMORY_SCOPE_AGENT);
        if (t == 255u) {
            __hip_atomic_store(&bar[0], 0u, __ATOMIC_RELAXED, __HIP_MEMORY_SCOPE_AGENT);
            __hip_atomic_store(&bar[1], g + 1u, __ATOMIC_RELEASE, __HIP_MEMORY_SCOPE_AGENT);
        } else {
            while (__hip_atomic_load(&bar[1], __ATOMIC_ACQUIRE, __HIP_MEMORY_SCOPE_AGENT) == g)
                __builtin_amdgcn_s_sleep(8);
        }
    }
    __syncthreads();
}

// Block 0: reduce per-sample boundary partials and write the final output.
__device__ void combine_out(int tid, float headLossSum,
                            const float* __restrict__ bps, const unsigned* __restrict__ bpc,
                            float* __restrict__ out)
{
    __shared__ float lf[256]; __shared__ unsigned lu[256];
    __shared__ float Pb[4], Nb[4]; __shared__ unsigned PCb[4], NCb[4];
    for (int b = 0; b < 4; ++b) {
        float ps = 0.f, ns = 0.f; unsigned p_c = 0, n_c = 0;
        if (tid < 128) {
            int j = b * 128 + tid;
            ps = bps[2 * j]; ns = bps[2 * j + 1];
            p_c = bpc[2 * j]; n_c = bpc[2 * j + 1];
        }
        lf[tid] = ps; lu[tid] = p_c; __syncthreads();
        for (int o = 128; o; o >>= 1) {
            if (tid < o) { lf[tid] += lf[tid + o]; lu[tid] += lu[tid + o]; }
            __syncthreads();
        }
        if (tid == 0) { Pb[b] = lf[0]; PCb[b] = lu[0]; }
        __syncthreads();
        lf[tid] = ns; lu[tid] = n_c; __syncthreads();
        for (int o = 128; o; o >>= 1) {
            if (tid < o) { lf[tid] += lf[tid + o]; lu[tid] += lu[tid + o]; }
            __syncthreads();
        }
        if (tid == 0) { Nb[b] = lf[0]; NCb[b] = lu[0]; }
        __syncthreads();
    }
    if (tid == 0) {
        float bt = 0.f;
        for (int b = 0; b < 4; ++b) {
            float pos = (float)PCb[b], neg = (float)NCb[b];
            float val = fmaxf(pos + neg, 1.f);
            bt += (neg / val) * Pb[b] + (pos / val) * Nb[b];
        }
        out[0] = headLossSum + bt / 2097152.0f;
    }
}

// ---------------------------------------------------------------------------
// Finisher (regular launch, 256 blocks). Every block redundantly reduces the
// pass1 partials (identical FP order => identical decision). Fast path:
// block 0 combines, others exit — no fences, no atomics. Slow path: exact
// radix select with software grid barriers.
// ---------------------------------------------------------------------------
__global__ __launch_bounds__(256) void finish_all(
    const float* __restrict__ probA, const int* __restrict__ seg,
    const float* __restrict__ ppsum, const unsigned* __restrict__ ppcnt,
    const float* __restrict__ bps, const unsigned* __restrict__ bpc,
    unsigned* __restrict__ hist, unsigned* __restrict__ bar,
    unsigned* __restrict__ prefix, unsigned* __restrict__ krem,
    float* __restrict__ thr,
    float* __restrict__ opsum, unsigned* __restrict__ opcnt,
    float* __restrict__ out)
{
    int tid = threadIdx.x, blk = blockIdx.x;
    int wave = tid >> 6, lane = tid & 63;

    // ---- redundant decide ----
    float s0 = 0.f, s1 = 0.f; unsigned c0 = 0u, c1 = 0u;
    for (int i = tid; i < 1024; i += 256) {
        s0 += ppsum[i];        c0 += ppcnt[i];
        s1 += ppsum[1024 + i]; c1 += ppcnt[1024 + i];
    }
    for (int o = 32; o; o >>= 1) {
        s0 += __shfl_down(s0, o, 64); s1 += __shfl_down(s1, o, 64);
        c0 += (unsigned)__shfl_down((int)c0, o, 64);
        c1 += (unsigned)__shfl_down((int)c1, o, 64);
    }
    __shared__ float ws0[4], ws1[4]; __shared__ unsigned wc0[4], wc1[4];
    if (lane == 0) { ws0[wave] = s0; ws1[wave] = s1; wc0[wave] = c0; wc1[wave] = c1; }
    __syncthreads();
    float S0 = ws0[0] + ws0[1] + ws0[2] + ws0[3];
    float S1 = ws1[0] + ws1[1] + ws1[2] + ws1[3];
    unsigned C0 = wc0[0] + wc0[1] + wc0[2] + wc0[3];
    unsigned C1 = wc1[0] + wc1[1] + wc1[2] + wc1[3];
    bool done0 = C0 >= 100000u, done1 = C1 >= 100000u;

    if (done0 && done1) {        // fast path: thr = 0.7 exactly for both heads
        if (blk == 0)
            combine_out(tid, S0 / fmaxf((float)C0, 1.f) + S1 / fmaxf((float)C1, 1.f),
                        bps, bpc, out);
        return;
    }

    // ---------------- slow path: exact radix select over float bits ----------------
    __shared__ unsigned hsh[4096];
    __shared__ unsigned cpre[257];
    unsigned doneMask = (done0 ? 1u : 0u) | (done1 ? 2u : 0u);

    for (int i = blk * 256 + tid; i < 24576; i += 65536) hist[i] = 0u;
    gbar(bar, tid);

    for (int lvl = 0; lvl < 3; ++lvl) {
        unsigned* hl = hist + lvl * 8192;
        for (int h = 0; h < 2; ++h) {
            if (doneMask & (1u << h)) continue;
            unsigned pre = (lvl == 0) ? 0u : prefix[h];
            for (int i = tid; i < 4096; i += 256) hsh[i] = 0u;
            __syncthreads();
            const float4* prob = (const float4*)(probA + (size_t)h * NPX);
            for (int i = blk * 256 + tid; i < NPX4; i += 65536) {
                float4 p = prob[i];
                unsigned u[4] = {__float_as_uint(p.x), __float_as_uint(p.y),
                                 __float_as_uint(p.z), __float_as_uint(p.w)};
#pragma unroll
                for (int k = 0; k < 4; ++k) {
                    unsigned bv = u[k];
                    if (lvl == 0)      atomicAdd(&hsh[bv >> 18], 1u);
                    else if (lvl == 1) { if ((bv >> 18) == pre) atomicAdd(&hsh[(bv >> 6) & 0xFFFu], 1u); }
                    else               { if ((bv >> 6) == pre) atomicAdd(&hsh[bv & 63u], 1u); }
                }
            }
            __syncthreads();
            for (int i = tid; i < 4096; i += 256) {
                unsigned v = hsh[i];
                if (v) atomicAdd(&hl[h * 4096 + i], v);
            }
            __syncthreads();
        }
        gbar(bar, tid);
        if (blk == 0) {
            int bins = (lvl == 2) ? 64 : 4096;
            for (int h = 0; h < 2; ++h) {
                if (doneMask & (1u << h)) continue;
                const unsigned* hh = hl + h * 4096;
                int per = (bins + 255) >> 8;
                int base = tid * per;
                unsigned ssum = 0;
                for (int i = 0; i < per; ++i) { int idx = base + i; if (idx < bins) ssum += hh[idx]; }
                cpre[tid] = ssum; __syncthreads();
                if (tid == 0) {
                    unsigned acc = 0;
                    for (int i = 0; i < 256; ++i) { unsigned v = cpre[i]; cpre[i] = acc; acc += v; }
                    cpre[256] = acc;
                }
                __syncthreads();
                unsigned K = (lvl == 0) ? 100000u : krem[h];
                unsigned my = cpre[tid], nx = cpre[tid + 1];
                if (K > 0 && my < K && K <= nx) {
                    unsigned acc = my;
                    for (int i = 0; i < per; ++i) {
                        int idx = base + i;
                        unsigned c = (idx < bins) ? hh[idx] : 0u;
                        if (acc < K && K <= acc + c) {
                            if (lvl == 0)      { prefix[h] = (unsigned)idx; krem[h] = K - acc; }
                            else if (lvl == 1) { prefix[h] = (prefix[h] << 12) | (unsigned)idx; krem[h] = K - acc; }
                            else {
                                unsigned bitsv = (prefix[h] << 6) | (unsigned)idx;
                                thr[h] = fmaxf(0.7f, __uint_as_float(bitsv));
                            }
                            break;
                        }
                        acc += c;
                    }
                }
                __syncthreads();
            }
        }
        gbar(bar, tid);
    }

    // masked reduce with exact thr (nll recomputed as -log(prob))
    for (int h = 0; h < 2; ++h) {
        if (doneMask & (1u << h)) continue;
        float th = thr[h];
        const float4* prob = (const float4*)(probA + (size_t)h * NPX);
        const int4*   sg4  = (const int4*)seg;
        float fs = 0.f; unsigned ic = 0;
        for (int i = blk * 256 + tid; i < NPX4; i += 65536) {
            float4 p = prob[i]; int4 tt = sg4[i];
            if (tt.x != 255 && p.x <= th) { fs -= __logf(p.x); ic++; }
            if (tt.y != 255 && p.y <= th) { fs -= __logf(p.y); ic++; }
            if (tt.z != 255 && p.z <= th) { fs -= __logf(p.z); ic++; }
            if (tt.w != 255 && p.w <= th) { fs -= __logf(p.w); ic++; }
        }
        for (int o = 32; o; o >>= 1) {
            fs += __shfl_down(fs, o, 64);
            ic += (unsigned)__shfl_down((int)ic, o, 64);
        }
        __shared__ float wf[4]; __shared__ unsigned wu[4];
        if (lane == 0) { wf[wave] = fs; wu[wave] = ic; }
        __syncthreads();
        if (tid == 0) {
            opsum[h * 256 + blk] = wf[0] + wf[1] + wf[2] + wf[3];
            opcnt[h * 256 + blk] = wu[0] + wu[1] + wu[2] + wu[3];
        }
        __syncthreads();
    }
    gbar(bar, tid);
    if (blk == 0) {
        __shared__ float lf2[256]; __shared__ unsigned lu2[256];
        float hls = 0.f;
        for (int h = 0; h < 2; ++h) {
            float S; unsigned C;
            if (doneMask & (1u << h)) {
                S = h ? S1 : S0; C = h ? C1 : C0;
            } else {
                lf2[tid] = opsum[h * 256 + tid]; lu2[tid] = opcnt[h * 256 + tid];
                __syncthreads();
                for (int o = 128; o; o >>= 1) {
                    if (tid < o) { lf2[tid] += lf2[tid + o]; lu2[tid] += lu2[tid + o]; }
                    __syncthreads();
                }
                S = lf2[0]; C = lu2[0];
                __syncthreads();
            }
            hls += S / fmaxf((float)C, 1.f);
        }
        combine_out(tid, hls, bps, bpc, out);
    }
}

extern "C" void kernel_launch(void* const* d_in, const int* in_sizes, int n_in,
                              void* d_out, int out_size, void* d_ws, size_t ws_size,
                              hipStream_t stream)
{
    const float* mp  = (const float*)d_in[0];
    const float* cp  = (const float*)d_in[1];
    const float* bp  = (const float*)d_in[2];
    const int*   seg = (const int*)d_in[3];
    const float* bg  = (const float*)d_in[4];
    float* out = (float*)d_out;

    char* ws = (char*)d_ws;
    float* probA = (float*)ws;
    unsigned* ctl    = (unsigned*)(ws + OFF_CTL);
    unsigned* hist   = ctl + CTL_HIST;
    unsigned* bar    = ctl + CTL_BAR;
    unsigned* prefix = ctl + CTL_PREFIX;
    unsigned* krem   = ctl + CTL_KREM;
    float*    thr    = (float*)(ctl + CTL_THR);
    float*    ppsum  = (float*)(ctl + CTL_PPSUM);
    unsigned* ppcnt  = ctl + CTL_PPCNT;
    float*    opsum  = (float*)(ctl + CTL_OPSUM);
    unsigned* opcnt  = ctl + CTL_OPCNT;
    float*    bps    = (float*)(ctl + CTL_BPS);
    unsigned* bpc    = ctl + CTL_BPC;

    fused_pass1<<<dim3(2560), 256, 0, stream>>>(mp, cp, bp, seg, bg, probA,
                                                ppsum, ppcnt, bps, bpc, bar);
    finish_all<<<dim3(256), 256, 0, stream>>>(probA, seg, ppsum, ppcnt, bps, bpc,
                                              hist, bar, prefix, krem, thr,
                                              opsum, opcnt, out);
}

// Round 8
// 114.708 us; speedup vs baseline: 1.0085x; 1.0085x over previous
//
#include <hip/hip_runtime.h>

// Problem constants
#define NPX    2097152                // 4*512*1024 pixels per head
#define NPX4   (NPX/4)
#define CH_STR 8192                   // 64*128
#define IMG_STR 155648                // 19*8192
#define LOG2E  1.4426950408889634f
#define LN2    0.6931471805599453f

// Workspace: prob[2*NPX] floats at ws start, control region after.
#define OFF_CTL   (2ull*NPX*4)
// ctl layout in u32 units
#define CTL_HIST    0                   // [3 levels][2 heads][4096] = 24576
#define CTL_BAR     24576               // u[2] software grid barrier (cnt, gen)
#define CTL_PREFIX  24578               // u[2]
#define CTL_KREM    24580               // u[2]
#define CTL_THR     24582               // f[2]
#define CTL_PPSUM   24584               // f[2*2048]
#define CTL_PPCNT   28680               // u[2*2048]
#define CTL_OPSUM   32776               // f[2*256]
#define CTL_OPCNT   33288               // u[2*256]
#define CTL_BPS     33800               // f[512*2]
#define CTL_BPC     34824               // u[512*2]

// ---------------------------------------------------------------------------
// Pass 1 (R6 structure): blocks [0,4096) = OHEM, ONE output row per block.
// Vertically-interpolated row staged in LDS as (e[x],e[x+1]) float2 pairs
// (branchless: er[x].x = e, er[(x-1)&127].y = e; the x=0 wrap writes a finite
// dummy to er[127].y which is only ever scaled by a zero weight).
// Horizontal lerp = 3-tap weighted sum with weights pre-scaled by log2(e);
// inner loop = 2 shared ds_read_b64 per channel + mul+fma+fma+v_exp+add.
// Blocks [4096,4608) = boundary BCE. No atomics; partials to private slots.
// ---------------------------------------------------------------------------
__global__ __launch_bounds__(256) void fused_pass1(
    const float* __restrict__ mp, const float* __restrict__ cp,
    const float* __restrict__ bp, const int* __restrict__ seg,
    const float* __restrict__ bg,
    float* __restrict__ probA, float* __restrict__ ppsum, unsigned* __restrict__ ppcnt,
    float* __restrict__ bps, unsigned* __restrict__ bpc, unsigned* __restrict__ bar)
{
    __shared__ float2 erow[19 * 128];          // 19.5 KB
    __shared__ float rf[4]; __shared__ unsigned ru[4];
    __shared__ float rf2[4]; __shared__ unsigned ru2[4];
    int bk = blockIdx.x;
    int tid = threadIdx.x;

    if (bk == 0 && tid < 2) bar[tid] = 0u;     // init software barrier

    if (bk < 4096) {
        int head = bk >> 11;
        int task = bk & 2047;                  // 2048 rows (4 samples * 512)
        int b = task >> 9;
        int y = task & 511;
        const float* pred = head ? cp : mp;

        float fy = (float)y * (63.0f / 511.0f);
        int y0 = min((int)fy, 63);
        int y1 = min(y0 + 1, 63);
        float wy = fy - (float)y0;

        const float* r0 = pred + (size_t)b * IMG_STR + y0 * 128;
        const float* r1 = pred + (size_t)b * IMG_STR + y1 * 128;
        for (int i = tid; i < 2432; i += 256) {      // 19*128
            int c = i >> 7, x = i & 127;
            float v0 = r0[c * CH_STR + x];
            float v1 = r1[c * CH_STR + x];
            float e = fmaf(wy, v1 - v0, v0);
            erow[c * 128 + x].x = e;
            erow[c * 128 + ((x - 1) & 127)].y = e;   // x=0 -> dummy in [127].y (0-weight)
        }
        __syncthreads();

        int xb = tid << 2;
        int P = (b * 512 + y) * 1024 + xb;           // per-head pixel index
        int4 t4 = *(const int4*)(seg + P);
        int t[4] = {t4.x, t4.y, t4.z, t4.w};

        float fx0 = (float)xb * (127.0f / 1023.0f);
        int X = min((int)fx0, 126);                  // taps e[X], e[X+1], e[X+2]
        float wA[4], wB[4], wC[4];
#pragma unroll
        for (int dx = 0; dx < 4; ++dx) {
            float fx = (float)(xb + dx) * (127.0f / 1023.0f);
            int x0 = min((int)fx, 127);
            float wx = fx - (float)x0;
            bool sm = (x0 == X);
            wA[dx] = sm ? (1.0f - wx) * LOG2E : 0.0f;      // weight on e[X]   (eA.x)
            wB[dx] = (sm ? wx : (1.0f - wx)) * LOG2E;      // weight on e[X+1] (eA.y)
            wC[dx] = sm ? 0.0f : wx * LOG2E;               // weight on e[X+2] (eB.y)
        }

        float s[4] = {0.f, 0.f, 0.f, 0.f};
#pragma unroll
        for (int c = 0; c < 19; ++c) {
            float2 eA = erow[c * 128 + X];           // (e[X],   e[X+1])
            float2 eB = erow[c * 128 + X + 1];       // (e[X+1], e[X+2])
#pragma unroll
            for (int dx = 0; dx < 4; ++dx) {
                float l2 = fmaf(eA.x, wA[dx], fmaf(eA.y, wB[dx], eB.y * wC[dx]));
                s[dx] += __builtin_exp2f(l2);        // v_exp_f32 (base 2)
            }
        }

        float fs = 0.f; unsigned ic = 0;
        float pr[4];
#pragma unroll
        for (int dx = 0; dx < 4; ++dx) {
            bool valid = (t[dx] != 255);
            int tc = valid ? t[dx] : 0;
            float2 eA = erow[tc * 128 + X];
            float2 eB = erow[tc * 128 + X + 1];
            float lt2 = fmaf(eA.x, wA[dx], fmaf(eA.y, wB[dx], eB.y * wC[dx]));  // bit-identical
            float ls2 = __builtin_log2f(s[dx]);      // v_log_f32
            float n   = LN2 * (ls2 - lt2);           // nll (natural log)
            float p   = fminf(__builtin_exp2f(lt2 - ls2), 1.0f);
            pr[dx] = valid ? p : 1.0f;               // mask_prob (matches reference)
            if (valid && p <= 0.7f) { fs += n; ic++; }
        }
        *(float4*)(probA + (size_t)head * NPX + P) = make_float4(pr[0], pr[1], pr[2], pr[3]);

        for (int o = 32; o; o >>= 1) {
            fs += __shfl_down(fs, o, 64);
            ic += (unsigned)__shfl_down((int)ic, o, 64);
        }
        int wave = tid >> 6, lane = tid & 63;
        if (lane == 0) { rf[wave] = fs; ru[wave] = ic; }
        __syncthreads();
        if (tid == 0) {
            ppsum[head * 2048 + task] = rf[0] + rf[1] + rf[2] + rf[3];
            ppcnt[head * 2048 + task] = ru[0] + ru[1] + ru[2] + ru[3];
        }
    } else {
        // -------- boundary BCE --------
        int bb = bk - 4096;                   // [0,512)
        int b  = bb >> 7;                     // 128 blocks per sample
        int blk = bb & 127;
        float psum = 0.f, nsum = 0.f; unsigned pc = 0, nc = 0;

        for (int g = blk * 256 + tid; g < 131072; g += 128 * 256) {
            int P = g << 2;
            int y = P >> 10, xb = P & 1023;

            float fy = (float)y * (63.0f / 511.0f);
            int y0 = min((int)fy, 63);
            int y1 = min(y0 + 1, 63);
            float wy = fy - (float)y0;

            const float* r0 = bp + b * 8192 + y0 * 128;
            const float* r1 = bp + b * 8192 + y1 * 128;
            float fx0 = (float)xb * (127.0f / 1023.0f);
            int X  = min((int)fx0, 126);
            int X2 = min(X + 2, 127);
            float c0 = r0[X], c1 = r0[X + 1], c2 = r0[X2];
            float d0 = r1[X], d1 = r1[X + 1], d2 = r1[X2];
            float e0 = fmaf(wy, d0 - c0, c0);
            float e1 = fmaf(wy, d1 - c1, c1);
            float e2 = fmaf(wy, d2 - c2, c2);

            float4 t4 = *(const float4*)(bg + (size_t)b * 524288 + P);
            float tv[4] = {t4.x, t4.y, t4.z, t4.w};

#pragma unroll
            for (int dx = 0; dx < 4; ++dx) {
                float fx = (float)(xb + dx) * (127.0f / 1023.0f);
                int x0 = min((int)fx, 127);
                int x1 = min(x0 + 1, 127);
                float wx = fx - (float)x0;
                float a0 = (x0 == X)     ? e0 : e1;
                float a1 = (x1 == X + 1) ? e1 : e2;
                float p  = fmaf(wx, a1 - a0, a0);
                bool isp = (tv[dx] == 1.0f);
                bool isn = (tv[dx] == 0.0f);
                float q = isp ? p : 1.0f - p;
                float l = fmaxf(__logf(q), -100.0f);
                if (isp) { pc++; psum -= l; }
                if (isn) { nc++; nsum -= l; }
            }
        }
        for (int o = 32; o; o >>= 1) {
            psum += __shfl_down(psum, o, 64);
            nsum += __shfl_down(nsum, o, 64);
            pc   += (unsigned)__shfl_down((int)pc, o, 64);
            nc   += (unsigned)__shfl_down((int)nc, o, 64);
        }
        int wave = tid >> 6, lane = tid & 63;
        if (lane == 0) { rf[wave] = psum; rf2[wave] = nsum; ru[wave] = pc; ru2[wave] = nc; }
        __syncthreads();
        if (tid == 0) {
            bps[2 * bb]     = rf[0] + rf[1] + rf[2] + rf[3];
            bps[2 * bb + 1] = rf2[0] + rf2[1] + rf2[2] + rf2[3];
            bpc[2 * bb]     = ru[0] + ru[1] + ru[2] + ru[3];
            bpc[2 * bb + 1] = ru2[0] + ru2[1] + ru2[2] + ru2[3];
        }
    }
}

// ---------------------------------------------------------------------------
// Software grid barrier (sense-reversing), agent scope. SLOW PATH ONLY.
// ---------------------------------------------------------------------------
__device__ __forceinline__ void gbar(unsigned* bar, int tid) {
    __syncthreads();
    if (tid == 0) {
        unsigned g = __hip_atomic_load(&bar[1], __ATOMIC_RELAXED, __HIP_MEMORY_SCOPE_AGENT);
        unsigned t = __hip_atomic_fetch_add(&bar[0], 1u, __ATOMIC_ACQ_REL, __HIP_MEMORY_SCOPE_AGENT);
        if (t == 255u) {
            __hip_atomic_store(&bar[0], 0u, __ATOMIC_RELAXED, __HIP_MEMORY_SCOPE_AGENT);
            __hip_atomic_store(&bar[1], g + 1u, __ATOMIC_RELEASE, __HIP_MEMORY_SCOPE_AGENT);
        } else {
            while (__hip_atomic_load(&bar[1], __ATOMIC_ACQUIRE, __HIP_MEMORY_SCOPE_AGENT) == g)
                __builtin_amdgcn_s_sleep(8);
        }
    }
    __syncthreads();
}

// Block 0: reduce per-sample boundary partials and write the final output.
__device__ void combine_out(int tid, float headLossSum,
                            const float* __restrict__ bps, const unsigned* __restrict__ bpc,
                            float* __restrict__ out)
{
    __shared__ float lf[256]; __shared__ unsigned lu[256];
    __shared__ float Pb[4], Nb[4]; __shared__ unsigned PCb[4], NCb[4];
    for (int b = 0; b < 4; ++b) {
        float ps = 0.f, ns = 0.f; unsigned p_c = 0, n_c = 0;
        if (tid < 128) {
            int j = b * 128 + tid;
            ps = bps[2 * j]; ns = bps[2 * j + 1];
            p_c = bpc[2 * j]; n_c = bpc[2 * j + 1];
        }
        lf[tid] = ps; lu[tid] = p_c; __syncthreads();
        for (int o = 128; o; o >>= 1) {
            if (tid < o) { lf[tid] += lf[tid + o]; lu[tid] += lu[tid + o]; }
            __syncthreads();
        }
        if (tid == 0) { Pb[b] = lf[0]; PCb[b] = lu[0]; }
        __syncthreads();
        lf[tid] = ns; lu[tid] = n_c; __syncthreads();
        for (int o = 128; o; o >>= 1) {
            if (tid < o) { lf[tid] += lf[tid + o]; lu[tid] += lu[tid + o]; }
            __syncthreads();
        }
        if (tid == 0) { Nb[b] = lf[0]; NCb[b] = lu[0]; }
        __syncthreads();
    }
    if (tid == 0) {
        float bt = 0.f;
        for (int b = 0; b < 4; ++b) {
            float pos = (float)PCb[b], neg = (float)NCb[b];
            float val = fmaxf(pos + neg, 1.f);
            bt += (neg / val) * Pb[b] + (pos / val) * Nb[b];
        }
        out[0] = headLossSum + bt / 2097152.0f;
    }
}

// ---------------------------------------------------------------------------
// Finisher (regular launch, 256 blocks). Every block redundantly reduces the
// pass1 partials (identical FP order => identical decision). Fast path:
// block 0 combines, others exit — no fences, no atomics. Slow path: exact
// radix select with software grid barriers.
// ---------------------------------------------------------------------------
__global__ __launch_bounds__(256) void finish_all(
    const float* __restrict__ probA, const int* __restrict__ seg,
    const float* __restrict__ ppsum, const unsigned* __restrict__ ppcnt,
    const float* __restrict__ bps, const unsigned* __restrict__ bpc,
    unsigned* __restrict__ hist, unsigned* __restrict__ bar,
    unsigned* __restrict__ prefix, unsigned* __restrict__ krem,
    float* __restrict__ thr,
    float* __restrict__ opsum, unsigned* __restrict__ opcnt,
    float* __restrict__ out)
{
    int tid = threadIdx.x, blk = blockIdx.x;
    int wave = tid >> 6, lane = tid & 63;

    // ---- redundant decide ----
    float s0 = 0.f, s1 = 0.f; unsigned c0 = 0u, c1 = 0u;
    for (int i = tid; i < 2048; i += 256) {
        s0 += ppsum[i];        c0 += ppcnt[i];
        s1 += ppsum[2048 + i]; c1 += ppcnt[2048 + i];
    }
    for (int o = 32; o; o >>= 1) {
        s0 += __shfl_down(s0, o, 64); s1 += __shfl_down(s1, o, 64);
        c0 += (unsigned)__shfl_down((int)c0, o, 64);
        c1 += (unsigned)__shfl_down((int)c1, o, 64);
    }
    __shared__ float ws0[4], ws1[4]; __shared__ unsigned wc0[4], wc1[4];
    if (lane == 0) { ws0[wave] = s0; ws1[wave] = s1; wc0[wave] = c0; wc1[wave] = c1; }
    __syncthreads();
    float S0 = ws0[0] + ws0[1] + ws0[2] + ws0[3];
    float S1 = ws1[0] + ws1[1] + ws1[2] + ws1[3];
    unsigned C0 = wc0[0] + wc0[1] + wc0[2] + wc0[3];
    unsigned C1 = wc1[0] + wc1[1] + wc1[2] + wc1[3];
    bool done0 = C0 >= 100000u, done1 = C1 >= 100000u;

    if (done0 && done1) {        // fast path: thr = 0.7 exactly for both heads
        if (blk == 0)
            combine_out(tid, S0 / fmaxf((float)C0, 1.f) + S1 / fmaxf((float)C1, 1.f),
                        bps, bpc, out);
        return;
    }

    // ---------------- slow path: exact radix select over float bits ----------------
    __shared__ unsigned hsh[4096];
    __shared__ unsigned cpre[257];
    unsigned doneMask = (done0 ? 1u : 0u) | (done1 ? 2u : 0u);

    for (int i = blk * 256 + tid; i < 24576; i += 65536) hist[i] = 0u;
    gbar(bar, tid);

    for (int lvl = 0; lvl < 3; ++lvl) {
        unsigned* hl = hist + lvl * 8192;
        for (int h = 0; h < 2; ++h) {
            if (doneMask & (1u << h)) continue;
            unsigned pre = (lvl == 0) ? 0u : prefix[h];
            for (int i = tid; i < 4096; i += 256) hsh[i] = 0u;
            __syncthreads();
            const float4* prob = (const float4*)(probA + (size_t)h * NPX);
            for (int i = blk * 256 + tid; i < NPX4; i += 65536) {
                float4 p = prob[i];
                unsigned u[4] = {__float_as_uint(p.x), __float_as_uint(p.y),
                                 __float_as_uint(p.z), __float_as_uint(p.w)};
#pragma unroll
                for (int k = 0; k < 4; ++k) {
                    unsigned bv = u[k];
                    if (lvl == 0)      atomicAdd(&hsh[bv >> 18], 1u);
                    else if (lvl == 1) { if ((bv >> 18) == pre) atomicAdd(&hsh[(bv >> 6) & 0xFFFu], 1u); }
                    else               { if ((bv >> 6) == pre) atomicAdd(&hsh[bv & 63u], 1u); }
                }
            }
            __syncthreads();
            for (int i = tid; i < 4096; i += 256) {
                unsigned v = hsh[i];
                if (v) atomicAdd(&hl[h * 4096 + i], v);
            }
            __syncthreads();
        }
        gbar(bar, tid);
        if (blk == 0) {
            int bins = (lvl == 2) ? 64 : 4096;
            for (int h = 0; h < 2; ++h) {
                if (doneMask & (1u << h)) continue;
                const unsigned* hh = hl + h * 4096;
                int per = (bins + 255) >> 8;
                int base = tid * per;
                unsigned ssum = 0;
                for (int i = 0; i < per; ++i) { int idx = base + i; if (idx < bins) ssum += hh[idx]; }
                cpre[tid] = ssum; __syncthreads();
                if (tid == 0) {
                    unsigned acc = 0;
                    for (int i = 0; i < 256; ++i) { unsigned v = cpre[i]; cpre[i] = acc; acc += v; }
                    cpre[256] = acc;
                }
                __syncthreads();
                unsigned K = (lvl == 0) ? 100000u : krem[h];
                unsigned my = cpre[tid], nx = cpre[tid + 1];
                if (K > 0 && my < K && K <= nx) {
                    unsigned acc = my;
                    for (int i = 0; i < per; ++i) {
                        int idx = base + i;
                        unsigned c = (idx < bins) ? hh[idx] : 0u;
                        if (acc < K && K <= acc + c) {
                            if (lvl == 0)      { prefix[h] = (unsigned)idx; krem[h] = K - acc; }
                            else if (lvl == 1) { prefix[h] = (prefix[h] << 12) | (unsigned)idx; krem[h] = K - acc; }
                            else {
                                unsigned bitsv = (prefix[h] << 6) | (unsigned)idx;
                                thr[h] = fmaxf(0.7f, __uint_as_float(bitsv));
                            }
                            break;
                        }
                        acc += c;
                    }
                }
                __syncthreads();
            }
        }
        gbar(bar, tid);
    }

    // masked reduce with exact thr (nll recomputed as -log(prob))
    for (int h = 0; h < 2; ++h) {
        if (doneMask & (1u << h)) continue;
        float th = thr[h];
        const float4* prob = (const float4*)(probA + (size_t)h * NPX);
        const int4*   sg4  = (const int4*)seg;
        float fs = 0.f; unsigned ic = 0;
        for (int i = blk * 256 + tid; i < NPX4; i += 65536) {
            float4 p = prob[i]; int4 tt = sg4[i];
            if (tt.x != 255 && p.x <= th) { fs -= __logf(p.x); ic++; }
            if (tt.y != 255 && p.y <= th) { fs -= __logf(p.y); ic++; }
            if (tt.z != 255 && p.z <= th) { fs -= __logf(p.z); ic++; }
            if (tt.w != 255 && p.w <= th) { fs -= __logf(p.w); ic++; }
        }
        for (int o = 32; o; o >>= 1) {
            fs += __shfl_down(fs, o, 64);
            ic += (unsigned)__shfl_down((int)ic, o, 64);
        }
        __shared__ float wf[4]; __shared__ unsigned wu[4];
        if (lane == 0) { wf[wave] = fs; wu[wave] = ic; }
        __syncthreads();
        if (tid == 0) {
            opsum[h * 256 + blk] = wf[0] + wf[1] + wf[2] + wf[3];
            opcnt[h * 256 + blk] = wu[0] + wu[1] + wu[2] + wu[3];
        }
        __syncthreads();
    }
    gbar(bar, tid);
    if (blk == 0) {
        __shared__ float lf2[256]; __shared__ unsigned lu2[256];
        float hls = 0.f;
        for (int h = 0; h < 2; ++h) {
            float S; unsigned C;
            if (doneMask & (1u << h)) {
                S = h ? S1 : S0; C = h ? C1 : C0;
            } else {
                lf2[tid] = opsum[h * 256 + tid]; lu2[tid] = opcnt[h * 256 + tid];
                __syncthreads();
                for (int o = 128; o; o >>= 1) {
                    if (tid < o) { lf2[tid] += lf2[tid + o]; lu2[tid] += lu2[tid + o]; }
                    __syncthreads();
                }
                S = lf2[0]; C = lu2[0];
                __syncthreads();
            }
            hls += S / fmaxf((float)C, 1.f);
        }
        combine_out(tid, hls, bps, bpc, out);
    }
}

extern "C" void kernel_launch(void* const* d_in, const int* in_sizes, int n_in,
                              void* d_out, int out_size, void* d_ws, size_t ws_size,
                              hipStream_t stream)
{
    const float* mp  = (const float*)d_in[0];
    const float* cp  = (const float*)d_in[1];
    const float* bp  = (const float*)d_in[2];
    const int*   seg = (const int*)d_in[3];
    const float* bg  = (const float*)d_in[4];
    float* out = (float*)d_out;

    char* ws = (char*)d_ws;
    float* probA = (float*)ws;
    unsigned* ctl    = (unsigned*)(ws + OFF_CTL);
    unsigned* hist   = ctl + CTL_HIST;
    unsigned* bar    = ctl + CTL_BAR;
    unsigned* prefix = ctl + CTL_PREFIX;
    unsigned* krem   = ctl + CTL_KREM;
    float*    thr    = (float*)(ctl + CTL_THR);
    float*    ppsum  = (float*)(ctl + CTL_PPSUM);
    unsigned* ppcnt  = ctl + CTL_PPCNT;
    float*    opsum  = (float*)(ctl + CTL_OPSUM);
    unsigned* opcnt  = ctl + CTL_OPCNT;
    float*    bps    = (float*)(ctl + CTL_BPS);
    unsigned* bpc    = ctl + CTL_BPC;

    fused_pass1<<<dim3(4608), 256, 0, stream>>>(mp, cp, bp, seg, bg, probA,
                                                ppsum, ppcnt, bps, bpc, bar);
    finish_all<<<dim3(256), 256, 0, stream>>>(probA, seg, ppsum, ppcnt, bps, bpc,
                                              hist, bar, prefix, krem, thr,
                                              opsum, opcnt, out);
}

// Round 9
// 114.150 us; speedup vs baseline: 1.0134x; 1.0049x over previous
//
#include <hip/hip_runtime.h>

// Problem constants
#define NPX    2097152                // 4*512*1024 pixels per head
#define NPX4   (NPX/4)
#define CH_STR 8192                   // 64*128
#define IMG_STR 155648                // 19*8192
#define LOG2E  1.4426950408889634f
#define LN2    0.6931471805599453f

// Workspace: prob[2*NPX] floats at ws start, control region after.
#define OFF_CTL   (2ull*NPX*4)
// ctl layout in u32 units
#define CTL_HIST    0                   // [3 levels][2 heads][4096] = 24576
#define CTL_BAR     24576               // u[2] software grid barrier (cnt, gen)
#define CTL_PREFIX  24578               // u[2]
#define CTL_KREM    24580               // u[2]
#define CTL_THR     24582               // f[2]
#define CTL_PPSUM   24584               // f[2*2048]
#define CTL_PPCNT   28680               // u[2*2048]
#define CTL_OPSUM   32776               // f[2*256]
#define CTL_OPCNT   33288               // u[2*256]
#define CTL_BPS     33800               // f[512*2]
#define CTL_BPC     34824               // u[512*2]

// ---------------------------------------------------------------------------
// Pass 1: blocks [0,4096) = OHEM, ONE output row per block (R6 structure —
// best occupancy/latency tradeoff measured: 19.5 KB LDS, VGPR ~32).
// Staging now uses float4 global loads (4x fewer load instrs + addressing).
// Vertically-interpolated row in LDS as (e[x],e[x+1]) float2 pairs; the x=0
// wrap writes a dummy to [127].y which only ever meets a zero weight.
// Horizontal lerp = 3-tap weighted sum, weights pre-scaled by log2(e);
// inner loop = 2 LDS pair-reads per channel + mul+fma+fma+v_exp+add per px.
// Blocks [4096,4608) = boundary BCE. No atomics; partials to private slots.
// ---------------------------------------------------------------------------
__global__ __launch_bounds__(256) void fused_pass1(
    const float* __restrict__ mp, const float* __restrict__ cp,
    const float* __restrict__ bp, const int* __restrict__ seg,
    const float* __restrict__ bg,
    float* __restrict__ probA, float* __restrict__ ppsum, unsigned* __restrict__ ppcnt,
    float* __restrict__ bps, unsigned* __restrict__ bpc, unsigned* __restrict__ bar)
{
    __shared__ float2 erow[19 * 128];          // 19.5 KB
    __shared__ float rf[4]; __shared__ unsigned ru[4];
    __shared__ float rf2[4]; __shared__ unsigned ru2[4];
    int bk = blockIdx.x;
    int tid = threadIdx.x;

    if (bk == 0 && tid < 2) bar[tid] = 0u;     // init software barrier

    if (bk < 4096) {
        int head = bk >> 11;
        int task = bk & 2047;                  // 2048 rows (4 samples * 512)
        int b = task >> 9;
        int y = task & 511;
        const float* pred = head ? cp : mp;

        float fy = (float)y * (63.0f / 511.0f);
        int y0 = min((int)fy, 63);
        int y1 = min(y0 + 1, 63);
        float wy = fy - (float)y0;

        const float* r0 = pred + (size_t)b * IMG_STR + y0 * 128;
        const float* r1 = pred + (size_t)b * IMG_STR + y1 * 128;
        // float4-vectorized staging: 608 = 19*32 float4s per source row
        for (int j = tid; j < 608; j += 256) {
            int c  = j >> 5;
            int x4 = (j & 31) << 2;
            const float* p0 = r0 + c * CH_STR + x4;
            const float* p1 = r1 + c * CH_STR + x4;
            float4 v0 = *(const float4*)p0;
            float4 v1 = *(const float4*)p1;
            float e0 = fmaf(wy, v1.x - v0.x, v0.x);
            float e1 = fmaf(wy, v1.y - v0.y, v0.y);
            float e2 = fmaf(wy, v1.z - v0.z, v0.z);
            float e3 = fmaf(wy, v1.w - v0.w, v0.w);
            float2* er = erow + c * 128;
            er[x4].x = e0; er[x4 + 1].x = e1; er[x4 + 2].x = e2; er[x4 + 3].x = e3;
            er[(x4 - 1) & 127].y = e0;         // x4=0 -> dummy in [127].y (0-weight)
            er[x4].y = e1; er[x4 + 1].y = e2; er[x4 + 2].y = e3;
        }
        __syncthreads();

        int xb = tid << 2;
        int P = (b * 512 + y) * 1024 + xb;           // per-head pixel index
        int4 t4 = *(const int4*)(seg + P);
        int t[4] = {t4.x, t4.y, t4.z, t4.w};

        float fx0 = (float)xb * (127.0f / 1023.0f);
        int X = min((int)fx0, 126);                  // taps e[X], e[X+1], e[X+2]
        float wA[4], wB[4], wC[4];
#pragma unroll
        for (int dx = 0; dx < 4; ++dx) {
            float fx = (float)(xb + dx) * (127.0f / 1023.0f);
            int x0 = min((int)fx, 127);
            float wx = fx - (float)x0;
            bool sm = (x0 == X);
            wA[dx] = sm ? (1.0f - wx) * LOG2E : 0.0f;      // weight on e[X]   (eA.x)
            wB[dx] = (sm ? wx : (1.0f - wx)) * LOG2E;      // weight on e[X+1] (eA.y)
            wC[dx] = sm ? 0.0f : wx * LOG2E;               // weight on e[X+2] (eB.y)
        }

        float s[4] = {0.f, 0.f, 0.f, 0.f};
#pragma unroll
        for (int c = 0; c < 19; ++c) {
            float2 eA = erow[c * 128 + X];           // (e[X],   e[X+1])
            float2 eB = erow[c * 128 + X + 1];       // (e[X+1], e[X+2])
#pragma unroll
            for (int dx = 0; dx < 4; ++dx) {
                float l2 = fmaf(eA.x, wA[dx], fmaf(eA.y, wB[dx], eB.y * wC[dx]));
                s[dx] += __builtin_exp2f(l2);        // v_exp_f32 (base 2)
            }
        }

        float fs = 0.f; unsigned ic = 0;
        float pr[4];
#pragma unroll
        for (int dx = 0; dx < 4; ++dx) {
            bool valid = (t[dx] != 255);
            int tc = valid ? t[dx] : 0;
            float2 eA = erow[tc * 128 + X];
            float2 eB = erow[tc * 128 + X + 1];
            float lt2 = fmaf(eA.x, wA[dx], fmaf(eA.y, wB[dx], eB.y * wC[dx]));  // bit-identical
            float ls2 = __builtin_log2f(s[dx]);      // v_log_f32
            float n   = LN2 * (ls2 - lt2);           // nll (natural log)
            float p   = fminf(__builtin_exp2f(lt2 - ls2), 1.0f);
            pr[dx] = valid ? p : 1.0f;               // mask_prob (matches reference)
            if (valid && p <= 0.7f) { fs += n; ic++; }
        }
        *(float4*)(probA + (size_t)head * NPX + P) = make_float4(pr[0], pr[1], pr[2], pr[3]);

        for (int o = 32; o; o >>= 1) {
            fs += __shfl_down(fs, o, 64);
            ic += (unsigned)__shfl_down((int)ic, o, 64);
        }
        int wave = tid >> 6, lane = tid & 63;
        if (lane == 0) { rf[wave] = fs; ru[wave] = ic; }
        __syncthreads();
        if (tid == 0) {
            ppsum[head * 2048 + task] = rf[0] + rf[1] + rf[2] + rf[3];
            ppcnt[head * 2048 + task] = ru[0] + ru[1] + ru[2] + ru[3];
        }
    } else {
        // -------- boundary BCE --------
        int bb = bk - 4096;                   // [0,512)
        int b  = bb >> 7;                     // 128 blocks per sample
        int blk = bb & 127;
        float psum = 0.f, nsum = 0.f; unsigned pc = 0, nc = 0;

        for (int g = blk * 256 + tid; g < 131072; g += 128 * 256) {
            int P = g << 2;
            int y = P >> 10, xb = P & 1023;

            float fy = (float)y * (63.0f / 511.0f);
            int y0 = min((int)fy, 63);
            int y1 = min(y0 + 1, 63);
            float wy = fy - (float)y0;

            const float* r0 = bp + b * 8192 + y0 * 128;
            const float* r1 = bp + b * 8192 + y1 * 128;
            float fx0 = (float)xb * (127.0f / 1023.0f);
            int X  = min((int)fx0, 126);
            int X2 = min(X + 2, 127);
            float c0 = r0[X], c1 = r0[X + 1], c2 = r0[X2];
            float d0 = r1[X], d1 = r1[X + 1], d2 = r1[X2];
            float e0 = fmaf(wy, d0 - c0, c0);
            float e1 = fmaf(wy, d1 - c1, c1);
            float e2 = fmaf(wy, d2 - c2, c2);

            float4 t4 = *(const float4*)(bg + (size_t)b * 524288 + P);
            float tv[4] = {t4.x, t4.y, t4.z, t4.w};

#pragma unroll
            for (int dx = 0; dx < 4; ++dx) {
                float fx = (float)(xb + dx) * (127.0f / 1023.0f);
                int x0 = min((int)fx, 127);
                int x1 = min(x0 + 1, 127);
                float wx = fx - (float)x0;
                float a0 = (x0 == X)     ? e0 : e1;
                float a1 = (x1 == X + 1) ? e1 : e2;
                float p  = fmaf(wx, a1 - a0, a0);
                bool isp = (tv[dx] == 1.0f);
                bool isn = (tv[dx] == 0.0f);
                float q = isp ? p : 1.0f - p;
                float l = fmaxf(__logf(q), -100.0f);
                if (isp) { pc++; psum -= l; }
                if (isn) { nc++; nsum -= l; }
            }
        }
        for (int o = 32; o; o >>= 1) {
            psum += __shfl_down(psum, o, 64);
            nsum += __shfl_down(nsum, o, 64);
            pc   += (unsigned)__shfl_down((int)pc, o, 64);
            nc   += (unsigned)__shfl_down((int)nc, o, 64);
        }
        int wave = tid >> 6, lane = tid & 63;
        if (lane == 0) { rf[wave] = psum; rf2[wave] = nsum; ru[wave] = pc; ru2[wave] = nc; }
        __syncthreads();
        if (tid == 0) {
            bps[2 * bb]     = rf[0] + rf[1] + rf[2] + rf[3];
            bps[2 * bb + 1] = rf2[0] + rf2[1] + rf2[2] + rf2[3];
            bpc[2 * bb]     = ru[0] + ru[1] + ru[2] + ru[3];
            bpc[2 * bb + 1] = ru2[0] + ru2[1] + ru2[2] + ru2[3];
        }
    }
}

// ---------------------------------------------------------------------------
// Software grid barrier (sense-reversing), agent scope. SLOW PATH ONLY.
// ---------------------------------------------------------------------------
__device__ __forceinline__ void gbar(unsigned* bar, int tid) {
    __syncthreads();
    if (tid == 0) {
        unsigned g = __hip_atomic_load(&bar[1], __ATOMIC_RELAXED, __HIP_MEMORY_SCOPE_AGENT);
        unsigned t = __hip_atomic_fetch_add(&bar[0], 1u, __ATOMIC_ACQ_REL, __HIP_MEMORY_SCOPE_AGENT);
        if (t == 255u) {
            __hip_atomic_store(&bar[0], 0u, __ATOMIC_RELAXED, __HIP_MEMORY_SCOPE_AGENT);
            __hip_atomic_store(&bar[1], g + 1u, __ATOMIC_RELEASE, __HIP_MEMORY_SCOPE_AGENT);
        } else {
            while (__hip_atomic_load(&bar[1], __ATOMIC_ACQUIRE, __HIP_MEMORY_SCOPE_AGENT) == g)
                __builtin_amdgcn_s_sleep(8);
        }
    }
    __syncthreads();
}

// Block 0: reduce per-sample boundary partials and write the final output.
__device__ void combine_out(int tid, float headLossSum,
                            const float* __restrict__ bps, const unsigned* __restrict__ bpc,
                            float* __restrict__ out)
{
    __shared__ float lf[256]; __shared__ unsigned lu[256];
    __shared__ float Pb[4], Nb[4]; __shared__ unsigned PCb[4], NCb[4];
    for (int b = 0; b < 4; ++b) {
        float ps = 0.f, ns = 0.f; unsigned p_c = 0, n_c = 0;
        if (tid < 128) {
            int j = b * 128 + tid;
            ps = bps[2 * j]; ns = bps[2 * j + 1];
            p_c = bpc[2 * j]; n_c = bpc[2 * j + 1];
        }
        lf[tid] = ps; lu[tid] = p_c; __syncthreads();
        for (int o = 128; o; o >>= 1) {
            if (tid < o) { lf[tid] += lf[tid + o]; lu[tid] += lu[tid + o]; }
            __syncthreads();
        }
        if (tid == 0) { Pb[b] = lf[0]; PCb[b] = lu[0]; }
        __syncthreads();
        lf[tid] = ns; lu[tid] = n_c; __syncthreads();
        for (int o = 128; o; o >>= 1) {
            if (tid < o) { lf[tid] += lf[tid + o]; lu[tid] += lu[tid + o]; }
            __syncthreads();
        }
        if (tid == 0) { Nb[b] = lf[0]; NCb[b] = lu[0]; }
        __syncthreads();
    }
    if (tid == 0) {
        float bt = 0.f;
        for (int b = 0; b < 4; ++b) {
            float pos = (float)PCb[b], neg = (float)NCb[b];
            float val = fmaxf(pos + neg, 1.f);
            bt += (neg / val) * Pb[b] + (pos / val) * Nb[b];
        }
        out[0] = headLossSum + bt / 2097152.0f;
    }
}

// ---------------------------------------------------------------------------
// Finisher (regular launch, 256 blocks). Every block redundantly reduces the
// pass1 partials (identical FP order => identical decision). Fast path:
// block 0 combines, others exit — no fences, no atomics. Slow path: exact
// radix select with software grid barriers.
// ---------------------------------------------------------------------------
__global__ __launch_bounds__(256) void finish_all(
    const float* __restrict__ probA, const int* __restrict__ seg,
    const float* __restrict__ ppsum, const unsigned* __restrict__ ppcnt,
    const float* __restrict__ bps, const unsigned* __restrict__ bpc,
    unsigned* __restrict__ hist, unsigned* __restrict__ bar,
    unsigned* __restrict__ prefix, unsigned* __restrict__ krem,
    float* __restrict__ thr,
    float* __restrict__ opsum, unsigned* __restrict__ opcnt,
    float* __restrict__ out)
{
    int tid = threadIdx.x, blk = blockIdx.x;
    int wave = tid >> 6, lane = tid & 63;

    // ---- redundant decide ----
    float s0 = 0.f, s1 = 0.f; unsigned c0 = 0u, c1 = 0u;
    for (int i = tid; i < 2048; i += 256) {
        s0 += ppsum[i];        c0 += ppcnt[i];
        s1 += ppsum[2048 + i]; c1 += ppcnt[2048 + i];
    }
    for (int o = 32; o; o >>= 1) {
        s0 += __shfl_down(s0, o, 64); s1 += __shfl_down(s1, o, 64);
        c0 += (unsigned)__shfl_down((int)c0, o, 64);
        c1 += (unsigned)__shfl_down((int)c1, o, 64);
    }
    __shared__ float ws0[4], ws1[4]; __shared__ unsigned wc0[4], wc1[4];
    if (lane == 0) { ws0[wave] = s0; ws1[wave] = s1; wc0[wave] = c0; wc1[wave] = c1; }
    __syncthreads();
    float S0 = ws0[0] + ws0[1] + ws0[2] + ws0[3];
    float S1 = ws1[0] + ws1[1] + ws1[2] + ws1[3];
    unsigned C0 = wc0[0] + wc0[1] + wc0[2] + wc0[3];
    unsigned C1 = wc1[0] + wc1[1] + wc1[2] + wc1[3];
    bool done0 = C0 >= 100000u, done1 = C1 >= 100000u;

    if (done0 && done1) {        // fast path: thr = 0.7 exactly for both heads
        if (blk == 0)
            combine_out(tid, S0 / fmaxf((float)C0, 1.f) + S1 / fmaxf((float)C1, 1.f),
                        bps, bpc, out);
        return;
    }

    // ---------------- slow path: exact radix select over float bits ----------------
    __shared__ unsigned hsh[4096];
    __shared__ unsigned cpre[257];
    unsigned doneMask = (done0 ? 1u : 0u) | (done1 ? 2u : 0u);

    for (int i = blk * 256 + tid; i < 24576; i += 65536) hist[i] = 0u;
    gbar(bar, tid);

    for (int lvl = 0; lvl < 3; ++lvl) {
        unsigned* hl = hist + lvl * 8192;
        for (int h = 0; h < 2; ++h) {
            if (doneMask & (1u << h)) continue;
            unsigned pre = (lvl == 0) ? 0u : prefix[h];
            for (int i = tid; i < 4096; i += 256) hsh[i] = 0u;
            __syncthreads();
            const float4* prob = (const float4*)(probA + (size_t)h * NPX);
            for (int i = blk * 256 + tid; i < NPX4; i += 65536) {
                float4 p = prob[i];
                unsigned u[4] = {__float_as_uint(p.x), __float_as_uint(p.y),
                                 __float_as_uint(p.z), __float_as_uint(p.w)};
#pragma unroll
                for (int k = 0; k < 4; ++k) {
                    unsigned bv = u[k];
                    if (lvl == 0)      atomicAdd(&hsh[bv >> 18], 1u);
                    else if (lvl == 1) { if ((bv >> 18) == pre) atomicAdd(&hsh[(bv >> 6) & 0xFFFu], 1u); }
                    else               { if ((bv >> 6) == pre) atomicAdd(&hsh[bv & 63u], 1u); }
                }
            }
            __syncthreads();
            for (int i = tid; i < 4096; i += 256) {
                unsigned v = hsh[i];
                if (v) atomicAdd(&hl[h * 4096 + i], v);
            }
            __syncthreads();
        }
        gbar(bar, tid);
        if (blk == 0) {
            int bins = (lvl == 2) ? 64 : 4096;
            for (int h = 0; h < 2; ++h) {
                if (doneMask & (1u << h)) continue;
                const unsigned* hh = hl + h * 4096;
                int per = (bins + 255) >> 8;
                int base = tid * per;
                unsigned ssum = 0;
                for (int i = 0; i < per; ++i) { int idx = base + i; if (idx < bins) ssum += hh[idx]; }
                cpre[tid] = ssum; __syncthreads();
                if (tid == 0) {
                    unsigned acc = 0;
                    for (int i = 0; i < 256; ++i) { unsigned v = cpre[i]; cpre[i] = acc; acc += v; }
                    cpre[256] = acc;
                }
                __syncthreads();
                unsigned K = (lvl == 0) ? 100000u : krem[h];
                unsigned my = cpre[tid], nx = cpre[tid + 1];
                if (K > 0 && my < K && K <= nx) {
                    unsigned acc = my;
                    for (int i = 0; i < per; ++i) {
                        int idx = base + i;
                        unsigned c = (idx < bins) ? hh[idx] : 0u;
                        if (acc < K && K <= acc + c) {
                            if (lvl == 0)      { prefix[h] = (unsigned)idx; krem[h] = K - acc; }
                            else if (lvl == 1) { prefix[h] = (prefix[h] << 12) | (unsigned)idx; krem[h] = K - acc; }
                            else {
                                unsigned bitsv = (prefix[h] << 6) | (unsigned)idx;
                                thr[h] = fmaxf(0.7f, __uint_as_float(bitsv));
                            }
                            break;
                        }
                        acc += c;
                    }
                }
                __syncthreads();
            }
        }
        gbar(bar, tid);
    }

    // masked reduce with exact thr (nll recomputed as -log(prob))
    for (int h = 0; h < 2; ++h) {
        if (doneMask & (1u << h)) continue;
        float th = thr[h];
        const float4* prob = (const float4*)(probA + (size_t)h * NPX);
        const int4*   sg4  = (const int4*)seg;
        float fs = 0.f; unsigned ic = 0;
        for (int i = blk * 256 + tid; i < NPX4; i += 65536) {
            float4 p = prob[i]; int4 tt = sg4[i];
            if (tt.x != 255 && p.x <= th) { fs -= __logf(p.x); ic++; }
            if (tt.y != 255 && p.y <= th) { fs -= __logf(p.y); ic++; }
            if (tt.z != 255 && p.z <= th) { fs -= __logf(p.z); ic++; }
            if (tt.w != 255 && p.w <= th) { fs -= __logf(p.w); ic++; }
        }
        for (int o = 32; o; o >>= 1) {
            fs += __shfl_down(fs, o, 64);
            ic += (unsigned)__shfl_down((int)ic, o, 64);
        }
        __shared__ float wf[4]; __shared__ unsigned wu[4];
        if (lane == 0) { wf[wave] = fs; wu[wave] = ic; }
        __syncthreads();
        if (tid == 0) {
            opsum[h * 256 + blk] = wf[0] + wf[1] + wf[2] + wf[3];
            opcnt[h * 256 + blk] = wu[0] + wu[1] + wu[2] + wu[3];
        }
        __syncthreads();
    }
    gbar(bar, tid);
    if (blk == 0) {
        __shared__ float lf2[256]; __shared__ unsigned lu2[256];
        float hls = 0.f;
        for (int h = 0; h < 2; ++h) {
            float S; unsigned C;
            if (doneMask & (1u << h)) {
                S = h ? S1 : S0; C = h ? C1 : C0;
            } else {
                lf2[tid] = opsum[h * 256 + tid]; lu2[tid] = opcnt[h * 256 + tid];
                __syncthreads();
                for (int o = 128; o; o >>= 1) {
                    if (tid < o) { lf2[tid] += lf2[tid + o]; lu2[tid] += lu2[tid + o]; }
                    __syncthreads();
                }
                S = lf2[0]; C = lu2[0];
                __syncthreads();
            }
            hls += S / fmaxf((float)C, 1.f);
        }
        combine_out(tid, hls, bps, bpc, out);
    }
}

extern "C" void kernel_launch(void* const* d_in, const int* in_sizes, int n_in,
                              void* d_out, int out_size, void* d_ws, size_t ws_size,
                              hipStream_t stream)
{
    const float* mp  = (const float*)d_in[0];
    const float* cp  = (const float*)d_in[1];
    const float* bp  = (const float*)d_in[2];
    const int*   seg = (const int*)d_in[3];
    const float* bg  = (const float*)d_in[4];
    float* out = (float*)d_out;

    char* ws = (char*)d_ws;
    float* probA = (float*)ws;
    unsigned* ctl    = (unsigned*)(ws + OFF_CTL);
    unsigned* hist   = ctl + CTL_HIST;
    unsigned* bar    = ctl + CTL_BAR;
    unsigned* prefix = ctl + CTL_PREFIX;
    unsigned* krem   = ctl + CTL_KREM;
    float*    thr    = (float*)(ctl + CTL_THR);
    float*    ppsum  = (float*)(ctl + CTL_PPSUM);
    unsigned* ppcnt  = ctl + CTL_PPCNT;
    float*    opsum  = (float*)(ctl + CTL_OPSUM);
    unsigned* opcnt  = ctl + CTL_OPCNT;
    float*    bps    = (float*)(ctl + CTL_BPS);
    unsigned* bpc    = ctl + CTL_BPC;

    fused_pass1<<<dim3(4608), 256, 0, stream>>>(mp, cp, bp, seg, bg, probA,
                                                ppsum, ppcnt, bps, bpc, bar);
    finish_all<<<dim3(256), 256, 0, stream>>>(probA, seg, ppsum, ppcnt, bps, bpc,
                                              hist, bar, prefix, krem, thr,
                                              opsum, opcnt, out);
}

// Round 10
// 109.243 us; speedup vs baseline: 1.0590x; 1.0449x over previous
//
#include <hip/hip_runtime.h>

// Problem constants
#define NPX    2097152                // 4*512*1024 pixels per head
#define NPX4   (NPX/4)
#define CH_STR 8192                   // 64*128
#define IMG_STR 155648                // 19*8192

// Workspace: prob[2*NPX] floats at ws start, control region after.
#define OFF_CTL   (2ull*NPX*4)
// ctl layout in u32 units
#define CTL_HIST    0                   // [3 levels][2 heads][4096] = 24576
#define CTL_BAR     24576               // u[2] software grid barrier (cnt, gen)
#define CTL_PREFIX  24578               // u[2]
#define CTL_KREM    24580               // u[2]
#define CTL_THR     24582               // f[2]
#define CTL_PPSUM   24584               // f[2*2048]
#define CTL_PPCNT   28680               // u[2*2048]
#define CTL_OPSUM   32776               // f[2*256]
#define CTL_OPCNT   33288               // u[2*256]
#define CTL_BPS     33800               // f[512*2]
#define CTL_BPC     34824               // u[512*2]

// ---------------------------------------------------------------------------
// Pass 1 (best-measured R6 variant): blocks [0,4096) = OHEM, one block per
// output row: stage vertically-interpolated row into LDS as (e[x],e[x+1])
// float2 pairs. Horizontal lerp as 3-tap weighted sum (wA,wB,wC over
// eA.x,eA.y,eB.y): inner loop = 2 shared ds_read_b64 per channel +
// mul+fma+fma+exp+add per px. Blocks [4096,4608) = boundary BCE.
// No atomics; partials to private slots.
// ---------------------------------------------------------------------------
__global__ __launch_bounds__(256) void fused_pass1(
    const float* __restrict__ mp, const float* __restrict__ cp,
    const float* __restrict__ bp, const int* __restrict__ seg,
    const float* __restrict__ bg,
    float* __restrict__ probA, float* __restrict__ ppsum, unsigned* __restrict__ ppcnt,
    float* __restrict__ bps, unsigned* __restrict__ bpc, unsigned* __restrict__ bar)
{
    __shared__ float2 erow[19 * 128];          // 19.5 KB
    __shared__ float rf[4]; __shared__ unsigned ru[4];
    __shared__ float rf2[4]; __shared__ unsigned ru2[4];
    int bk = blockIdx.x;
    int tid = threadIdx.x;

    if (bk == 0 && tid < 2) bar[tid] = 0u;     // init software barrier

    if (bk < 4096) {
        int head = bk >> 11;
        int task = bk & 2047;                  // 2048 rows (4 samples * 512)
        int b = task >> 9;
        int y = task & 511;
        const float* pred = head ? cp : mp;

        float fy = (float)y * (63.0f / 511.0f);
        int y0 = min((int)fy, 63);
        int y1 = min(y0 + 1, 63);
        float wy = fy - (float)y0;

        const float* r0 = pred + (size_t)b * IMG_STR + y0 * 128;
        const float* r1 = pred + (size_t)b * IMG_STR + y1 * 128;
        for (int i = tid; i < 2432; i += 256) {      // 19*128
            int c = i >> 7, x = i & 127;
            float v0 = r0[c * CH_STR + x];
            float v1 = r1[c * CH_STR + x];
            float e = fmaf(wy, v1 - v0, v0);
            erow[c * 128 + x].x = e;
            if (x > 0)    erow[c * 128 + x - 1].y = e;
            if (x == 127) erow[c * 128 + 127].y = e;   // pad; weight is 0 there
        }
        __syncthreads();

        int xb = tid << 2;
        int P = (b * 512 + y) * 1024 + xb;           // per-head pixel index
        int4 t4 = *(const int4*)(seg + P);
        int t[4] = {t4.x, t4.y, t4.z, t4.w};

        float fx0 = (float)xb * (127.0f / 1023.0f);
        int X = min((int)fx0, 126);                  // taps e[X], e[X+1], e[X+2]
        float wA[4], wB[4], wC[4];
#pragma unroll
        for (int dx = 0; dx < 4; ++dx) {
            float fx = (float)(xb + dx) * (127.0f / 1023.0f);
            int x0 = min((int)fx, 127);
            float wx = fx - (float)x0;
            bool sm = (x0 == X);
            wA[dx] = sm ? (1.0f - wx) : 0.0f;        // weight on e[X]   (eA.x)
            wB[dx] = sm ? wx : (1.0f - wx);          // weight on e[X+1] (eA.y)
            wC[dx] = sm ? 0.0f : wx;                 // weight on e[X+2] (eB.y)
        }

        float s[4] = {0.f, 0.f, 0.f, 0.f};
        for (int c = 0; c < 19; ++c) {
            float2 eA = erow[c * 128 + X];           // (e[X],   e[X+1])
            float2 eB = erow[c * 128 + X + 1];       // (e[X+1], e[X+2])
#pragma unroll
            for (int dx = 0; dx < 4; ++dx) {
                float l = fmaf(eA.x, wA[dx], fmaf(eA.y, wB[dx], eB.y * wC[dx]));
                s[dx] += __expf(l);
            }
        }

        float fs = 0.f; unsigned ic = 0;
        float pr[4];
#pragma unroll
        for (int dx = 0; dx < 4; ++dx) {
            bool valid = (t[dx] != 255);
            int tc = valid ? t[dx] : 0;
            float2 eA = erow[tc * 128 + X];
            float2 eB = erow[tc * 128 + X + 1];
            float lt = fmaf(eA.x, wA[dx], fmaf(eA.y, wB[dx], eB.y * wC[dx]));  // bit-identical
            float ls = __logf(s[dx]);
            float n  = ls - lt;                      // nll at target
            float p  = fminf(__expf(-n), 1.0f);
            pr[dx] = valid ? p : 1.0f;               // mask_prob (matches reference)
            if (valid && p <= 0.7f) { fs += n; ic++; }
        }
        *(float4*)(probA + (size_t)head * NPX + P) = make_float4(pr[0], pr[1], pr[2], pr[3]);

        for (int o = 32; o; o >>= 1) {
            fs += __shfl_down(fs, o, 64);
            ic += (unsigned)__shfl_down((int)ic, o, 64);
        }
        int wave = tid >> 6, lane = tid & 63;
        if (lane == 0) { rf[wave] = fs; ru[wave] = ic; }
        __syncthreads();
        if (tid == 0) {
            ppsum[head * 2048 + task] = rf[0] + rf[1] + rf[2] + rf[3];
            ppcnt[head * 2048 + task] = ru[0] + ru[1] + ru[2] + ru[3];
        }
    } else {
        // -------- boundary BCE --------
        int bb = bk - 4096;                   // [0,512)
        int b  = bb >> 7;                     // 128 blocks per sample
        int blk = bb & 127;
        float psum = 0.f, nsum = 0.f; unsigned pc = 0, nc = 0;

        for (int g = blk * 256 + tid; g < 131072; g += 128 * 256) {
            int P = g << 2;
            int y = P >> 10, xb = P & 1023;

            float fy = (float)y * (63.0f / 511.0f);
            int y0 = min((int)fy, 63);
            int y1 = min(y0 + 1, 63);
            float wy = fy - (float)y0;

            const float* r0 = bp + b * 8192 + y0 * 128;
            const float* r1 = bp + b * 8192 + y1 * 128;
            float fx0 = (float)xb * (127.0f / 1023.0f);
            int X  = min((int)fx0, 126);
            int X2 = min(X + 2, 127);
            float c0 = r0[X], c1 = r0[X + 1], c2 = r0[X2];
            float d0 = r1[X], d1 = r1[X + 1], d2 = r1[X2];
            float e0 = fmaf(wy, d0 - c0, c0);
            float e1 = fmaf(wy, d1 - c1, c1);
            float e2 = fmaf(wy, d2 - c2, c2);

            float4 t4 = *(const float4*)(bg + (size_t)b * 524288 + P);
            float tv[4] = {t4.x, t4.y, t4.z, t4.w};

#pragma unroll
            for (int dx = 0; dx < 4; ++dx) {
                float fx = (float)(xb + dx) * (127.0f / 1023.0f);
                int x0 = min((int)fx, 127);
                int x1 = min(x0 + 1, 127);
                float wx = fx - (float)x0;
                float a0 = (x0 == X)     ? e0 : e1;
                float a1 = (x1 == X + 1) ? e1 : e2;
                float p  = fmaf(wx, a1 - a0, a0);
                bool isp = (tv[dx] == 1.0f);
                bool isn = (tv[dx] == 0.0f);
                float q = isp ? p : 1.0f - p;
                float l = fmaxf(__logf(q), -100.0f);
                if (isp) { pc++; psum -= l; }
                if (isn) { nc++; nsum -= l; }
            }
        }
        for (int o = 32; o; o >>= 1) {
            psum += __shfl_down(psum, o, 64);
            nsum += __shfl_down(nsum, o, 64);
            pc   += (unsigned)__shfl_down((int)pc, o, 64);
            nc   += (unsigned)__shfl_down((int)nc, o, 64);
        }
        int wave = tid >> 6, lane = tid & 63;
        if (lane == 0) { rf[wave] = psum; rf2[wave] = nsum; ru[wave] = pc; ru2[wave] = nc; }
        __syncthreads();
        if (tid == 0) {
            bps[2 * bb]     = rf[0] + rf[1] + rf[2] + rf[3];
            bps[2 * bb + 1] = rf2[0] + rf2[1] + rf2[2] + rf2[3];
            bpc[2 * bb]     = ru[0] + ru[1] + ru[2] + ru[3];
            bpc[2 * bb + 1] = ru2[0] + ru2[1] + ru2[2] + ru2[3];
        }
    }
}

// ---------------------------------------------------------------------------
// Software grid barrier (sense-reversing), agent scope. SLOW PATH ONLY.
// ---------------------------------------------------------------------------
__device__ __forceinline__ void gbar(unsigned* bar, int tid) {
    __syncthreads();
    if (tid == 0) {
        unsigned g = __hip_atomic_load(&bar[1], __ATOMIC_RELAXED, __HIP_MEMORY_SCOPE_AGENT);
        unsigned t = __hip_atomic_fetch_add(&bar[0], 1u, __ATOMIC_ACQ_REL, __HIP_MEMORY_SCOPE_AGENT);
        if (t == 255u) {
            __hip_atomic_store(&bar[0], 0u, __ATOMIC_RELAXED, __HIP_MEMORY_SCOPE_AGENT);
            __hip_atomic_store(&bar[1], g + 1u, __ATOMIC_RELEASE, __HIP_MEMORY_SCOPE_AGENT);
        } else {
            while (__hip_atomic_load(&bar[1], __ATOMIC_ACQUIRE, __HIP_MEMORY_SCOPE_AGENT) == g)
                __builtin_amdgcn_s_sleep(8);
        }
    }
    __syncthreads();
}

// Block 0: reduce per-sample boundary partials and write the final output.
__device__ void combine_out(int tid, float headLossSum,
                            const float* __restrict__ bps, const unsigned* __restrict__ bpc,
                            float* __restrict__ out)
{
    __shared__ float lf[256]; __shared__ unsigned lu[256];
    __shared__ float Pb[4], Nb[4]; __shared__ unsigned PCb[4], NCb[4];
    for (int b = 0; b < 4; ++b) {
        float ps = 0.f, ns = 0.f; unsigned p_c = 0, n_c = 0;
        if (tid < 128) {
            int j = b * 128 + tid;
            ps = bps[2 * j]; ns = bps[2 * j + 1];
            p_c = bpc[2 * j]; n_c = bpc[2 * j + 1];
        }
        lf[tid] = ps; lu[tid] = p_c; __syncthreads();
        for (int o = 128; o; o >>= 1) {
            if (tid < o) { lf[tid] += lf[tid + o]; lu[tid] += lu[tid + o]; }
            __syncthreads();
        }
        if (tid == 0) { Pb[b] = lf[0]; PCb[b] = lu[0]; }
        __syncthreads();
        lf[tid] = ns; lu[tid] = n_c; __syncthreads();
        for (int o = 128; o; o >>= 1) {
            if (tid < o) { lf[tid] += lf[tid + o]; lu[tid] += lu[tid + o]; }
            __syncthreads();
        }
        if (tid == 0) { Nb[b] = lf[0]; NCb[b] = lu[0]; }
        __syncthreads();
    }
    if (tid == 0) {
        float bt = 0.f;
        for (int b = 0; b < 4; ++b) {
            float pos = (float)PCb[b], neg = (float)NCb[b];
            float val = fmaxf(pos + neg, 1.f);
            bt += (neg / val) * Pb[b] + (pos / val) * Nb[b];
        }
        out[0] = headLossSum + bt / 2097152.0f;
    }
}

// ---------------------------------------------------------------------------
// Finisher (regular launch, 256 blocks). Every block redundantly reduces the
// pass1 partials (identical FP order => identical decision). Fast path:
// block 0 combines, others exit — no fences, no atomics. Slow path: exact
// radix select with software grid barriers.
// ---------------------------------------------------------------------------
__global__ __launch_bounds__(256) void finish_all(
    const float* __restrict__ probA, const int* __restrict__ seg,
    const float* __restrict__ ppsum, const unsigned* __restrict__ ppcnt,
    const float* __restrict__ bps, const unsigned* __restrict__ bpc,
    unsigned* __restrict__ hist, unsigned* __restrict__ bar,
    unsigned* __restrict__ prefix, unsigned* __restrict__ krem,
    float* __restrict__ thr,
    float* __restrict__ opsum, unsigned* __restrict__ opcnt,
    float* __restrict__ out)
{
    int tid = threadIdx.x, blk = blockIdx.x;
    int wave = tid >> 6, lane = tid & 63;

    // ---- redundant decide ----
    float s0 = 0.f, s1 = 0.f; unsigned c0 = 0u, c1 = 0u;
    for (int i = tid; i < 2048; i += 256) {
        s0 += ppsum[i];        c0 += ppcnt[i];
        s1 += ppsum[2048 + i]; c1 += ppcnt[2048 + i];
    }
    for (int o = 32; o; o >>= 1) {
        s0 += __shfl_down(s0, o, 64); s1 += __shfl_down(s1, o, 64);
        c0 += (unsigned)__shfl_down((int)c0, o, 64);
        c1 += (unsigned)__shfl_down((int)c1, o, 64);
    }
    __shared__ float ws0[4], ws1[4]; __shared__ unsigned wc0[4], wc1[4];
    if (lane == 0) { ws0[wave] = s0; ws1[wave] = s1; wc0[wave] = c0; wc1[wave] = c1; }
    __syncthreads();
    float S0 = ws0[0] + ws0[1] + ws0[2] + ws0[3];
    float S1 = ws1[0] + ws1[1] + ws1[2] + ws1[3];
    unsigned C0 = wc0[0] + wc0[1] + wc0[2] + wc0[3];
    unsigned C1 = wc1[0] + wc1[1] + wc1[2] + wc1[3];
    bool done0 = C0 >= 100000u, done1 = C1 >= 100000u;

    if (done0 && done1) {        // fast path: thr = 0.7 exactly for both heads
        if (blk == 0)
            combine_out(tid, S0 / fmaxf((float)C0, 1.f) + S1 / fmaxf((float)C1, 1.f),
                        bps, bpc, out);
        return;
    }

    // ---------------- slow path: exact radix select over float bits ----------------
    __shared__ unsigned hsh[4096];
    __shared__ unsigned cpre[257];
    unsigned doneMask = (done0 ? 1u : 0u) | (done1 ? 2u : 0u);

    for (int i = blk * 256 + tid; i < 24576; i += 65536) hist[i] = 0u;
    gbar(bar, tid);

    for (int lvl = 0; lvl < 3; ++lvl) {
        unsigned* hl = hist + lvl * 8192;
        for (int h = 0; h < 2; ++h) {
            if (doneMask & (1u << h)) continue;
            unsigned pre = (lvl == 0) ? 0u : prefix[h];
            for (int i = tid; i < 4096; i += 256) hsh[i] = 0u;
            __syncthreads();
            const float4* prob = (const float4*)(probA + (size_t)h * NPX);
            for (int i = blk * 256 + tid; i < NPX4; i += 65536) {
                float4 p = prob[i];
                unsigned u[4] = {__float_as_uint(p.x), __float_as_uint(p.y),
                                 __float_as_uint(p.z), __float_as_uint(p.w)};
#pragma unroll
                for (int k = 0; k < 4; ++k) {
                    unsigned bv = u[k];
                    if (lvl == 0)      atomicAdd(&hsh[bv >> 18], 1u);
                    else if (lvl == 1) { if ((bv >> 18) == pre) atomicAdd(&hsh[(bv >> 6) & 0xFFFu], 1u); }
                    else               { if ((bv >> 6) == pre) atomicAdd(&hsh[bv & 63u], 1u); }
                }
            }
            __syncthreads();
            for (int i = tid; i < 4096; i += 256) {
                unsigned v = hsh[i];
                if (v) atomicAdd(&hl[h * 4096 + i], v);
            }
            __syncthreads();
        }
        gbar(bar, tid);
        if (blk == 0) {
            int bins = (lvl == 2) ? 64 : 4096;
            for (int h = 0; h < 2; ++h) {
                if (doneMask & (1u << h)) continue;
                const unsigned* hh = hl + h * 4096;
                int per = (bins + 255) >> 8;
                int base = tid * per;
                unsigned ssum = 0;
                for (int i = 0; i < per; ++i) { int idx = base + i; if (idx < bins) ssum += hh[idx]; }
                cpre[tid] = ssum; __syncthreads();
                if (tid == 0) {
                    unsigned acc = 0;
                    for (int i = 0; i < 256; ++i) { unsigned v = cpre[i]; cpre[i] = acc; acc += v; }
                    cpre[256] = acc;
                }
                __syncthreads();
                unsigned K = (lvl == 0) ? 100000u : krem[h];
                unsigned my = cpre[tid], nx = cpre[tid + 1];
                if (K > 0 && my < K && K <= nx) {
                    unsigned acc = my;
                    for (int i = 0; i < per; ++i) {
                        int idx = base + i;
                        unsigned c = (idx < bins) ? hh[idx] : 0u;
                        if (acc < K && K <= acc + c) {
                            if (lvl == 0)      { prefix[h] = (unsigned)idx; krem[h] = K - acc; }
                            else if (lvl == 1) { prefix[h] = (prefix[h] << 12) | (unsigned)idx; krem[h] = K - acc; }
                            else {
                                unsigned bitsv = (prefix[h] << 6) | (unsigned)idx;
                                thr[h] = fmaxf(0.7f, __uint_as_float(bitsv));
                            }
                            break;
                        }
                        acc += c;
                    }
                }
                __syncthreads();
            }
        }
        gbar(bar, tid);
    }

    // masked reduce with exact thr (nll recomputed as -log(prob))
    for (int h = 0; h < 2; ++h) {
        if (doneMask & (1u << h)) continue;
        float th = thr[h];
        const float4* prob = (const float4*)(probA + (size_t)h * NPX);
        const int4*   sg4  = (const int4*)seg;
        float fs = 0.f; unsigned ic = 0;
        for (int i = blk * 256 + tid; i < NPX4; i += 65536) {
            float4 p = prob[i]; int4 tt = sg4[i];
            if (tt.x != 255 && p.x <= th) { fs -= __logf(p.x); ic++; }
            if (tt.y != 255 && p.y <= th) { fs -= __logf(p.y); ic++; }
            if (tt.z != 255 && p.z <= th) { fs -= __logf(p.z); ic++; }
            if (tt.w != 255 && p.w <= th) { fs -= __logf(p.w); ic++; }
        }
        for (int o = 32; o; o >>= 1) {
            fs += __shfl_down(fs, o, 64);
            ic += (unsigned)__shfl_down((int)ic, o, 64);
        }
        __shared__ float wf[4]; __shared__ unsigned wu[4];
        if (lane == 0) { wf[wave] = fs; wu[wave] = ic; }
        __syncthreads();
        if (tid == 0) {
            opsum[h * 256 + blk] = wf[0] + wf[1] + wf[2] + wf[3];
            opcnt[h * 256 + blk] = wu[0] + wu[1] + wu[2] + wu[3];
        }
        __syncthreads();
    }
    gbar(bar, tid);
    if (blk == 0) {
        __shared__ float lf2[256]; __shared__ unsigned lu2[256];
        float hls = 0.f;
        for (int h = 0; h < 2; ++h) {
            float S; unsigned C;
            if (doneMask & (1u << h)) {
                S = h ? S1 : S0; C = h ? C1 : C0;
            } else {
                lf2[tid] = opsum[h * 256 + tid]; lu2[tid] = opcnt[h * 256 + tid];
                __syncthreads();
                for (int o = 128; o; o >>= 1) {
                    if (tid < o) { lf2[tid] += lf2[tid + o]; lu2[tid] += lu2[tid + o]; }
                    __syncthreads();
                }
                S = lf2[0]; C = lu2[0];
                __syncthreads();
            }
            hls += S / fmaxf((float)C, 1.f);
        }
        combine_out(tid, hls, bps, bpc, out);
    }
}

extern "C" void kernel_launch(void* const* d_in, const int* in_sizes, int n_in,
                              void* d_out, int out_size, void* d_ws, size_t ws_size,
                              hipStream_t stream)
{
    const float* mp  = (const float*)d_in[0];
    const float* cp  = (const float*)d_in[1];
    const float* bp  = (const float*)d_in[2];
    const int*   seg = (const int*)d_in[3];
    const float* bg  = (const float*)d_in[4];
    float* out = (float*)d_out;

    char* ws = (char*)d_ws;
    float* probA = (float*)ws;
    unsigned* ctl    = (unsigned*)(ws + OFF_CTL);
    unsigned* hist   = ctl + CTL_HIST;
    unsigned* bar    = ctl + CTL_BAR;
    unsigned* prefix = ctl + CTL_PREFIX;
    unsigned* krem   = ctl + CTL_KREM;
    float*    thr    = (float*)(ctl + CTL_THR);
    float*    ppsum  = (float*)(ctl + CTL_PPSUM);
    unsigned* ppcnt  = ctl + CTL_PPCNT;
    float*    opsum  = (float*)(ctl + CTL_OPSUM);
    unsigned* opcnt  = ctl + CTL_OPCNT;
    float*    bps    = (float*)(ctl + CTL_BPS);
    unsigned* bpc    = ctl + CTL_BPC;

    fused_pass1<<<dim3(4608), 256, 0, stream>>>(mp, cp, bp, seg, bg, probA,
                                                ppsum, ppcnt, bps, bpc, bar);
    finish_all<<<dim3(256), 256, 0, stream>>>(probA, seg, ppsum, ppcnt, bps, bpc,
                                              hist, bar, prefix, krem, thr,
                                              opsum, opcnt, out);
}